// Round 1
// baseline (771.555 us; speedup 1.0000x reference)
//
#include <hip/hip_runtime.h>
#include <hip/hip_bf16.h>

// Problem constants
#define H_   32
#define KV_  8
#define D_   128
#define S_   2048
#define HID_ 4096

typedef __attribute__((ext_vector_type(8))) short short8;
typedef short8 short8a __attribute__((may_alias));
typedef __attribute__((ext_vector_type(4))) float f32x4;
typedef unsigned short u16;

__device__ __forceinline__ u16 f2bf(float f) {
  union { float f; unsigned u; } a; a.f = f;
  unsigned r = a.u + 0x7fffu + ((a.u >> 16) & 1u);   // RNE
  return (u16)(r >> 16);
}
__device__ __forceinline__ float bf2f(u16 h) {
  union { unsigned u; float f; } a; a.u = ((unsigned)h) << 16;
  return a.f;
}

#define GLOAD16(g, l) __builtin_amdgcn_global_load_lds( \
    (const __attribute__((address_space(1))) void*)(g), \
    (__attribute__((address_space(3))) void*)(l), 16, 0, 0)

// ---------------- elementwise fp32 -> bf16 cast ----------------
__global__ void cast_kernel(const float* __restrict__ in, u16* __restrict__ out, int n4) {
  int i = blockIdx.x * blockDim.x + threadIdx.x;
  int stride = gridDim.x * blockDim.x;
  for (; i < n4; i += stride) {
    float4 v = ((const float4*)in)[i];
    ushort4 o;
    o.x = f2bf(v.x); o.y = f2bf(v.y); o.z = f2bf(v.z); o.w = f2bf(v.w);
    ((ushort4*)out)[i] = o;
  }
}

// ---------------- X (HID,S) fp32 -> X^T (S,HID) bf16 ----------------
__global__ __launch_bounds__(256) void transpose_cast_kernel(const float* __restrict__ in,
                                                             u16* __restrict__ out) {
  __shared__ float t[32][33];
  int tx = threadIdx.x & 31, ty = threadIdx.x >> 5;  // 32x8
  int s0 = blockIdx.x * 32, c0 = blockIdx.y * 32;
  #pragma unroll
  for (int i = 0; i < 4; i++)
    t[ty + i * 8][tx] = in[(size_t)(c0 + ty + i * 8) * S_ + s0 + tx];
  __syncthreads();
  #pragma unroll
  for (int i = 0; i < 4; i++)
    out[(size_t)(s0 + ty + i * 8) * HID_ + c0 + tx] = f2bf(t[tx][ty + i * 8]);
}

// ---------------- bf16 GEMM: C(MxN) = A(MxK) * Bt(NxK)^T (+bias) ----------------
// m97 structure: 128x128 tile, BK=32, 4 waves (2x2), global_load_lds staging.
__global__ __launch_bounds__(256) void gemm_bt(const u16* __restrict__ A, const u16* __restrict__ Bt,
                                               const float* __restrict__ bias,
                                               u16* __restrict__ Cb, float* __restrict__ Cf,
                                               int M, int N, int K) {
  __shared__ alignas(16) u16 As[128 * 32];
  __shared__ alignas(16) u16 Bs[128 * 32];
  int tid = threadIdx.x, wid = tid >> 6, lane = tid & 63;
  int lr = lane & 15, kg = lane >> 4;
  int m0 = blockIdx.y * 128, n0 = blockIdx.x * 128;
  int wr = wid >> 1, wc = wid & 1;
  f32x4 acc[4][4] = {};
  int c0 = wid * 2, c1 = wid * 2 + 1;          // 1KB LDS chunks staged by this wave
  int ar0 = c0 * 16 + (lane >> 2);             // tile row for this lane's 16B
  int ar1 = c1 * 16 + (lane >> 2);
  int kb = (lane & 3) * 16;                    // byte offset within 64B row
  const char* Ac = (const char*)A;
  const char* Bc = (const char*)Bt;
  for (int kt = 0; kt < K; kt += 32) {
    GLOAD16(Ac + ((size_t)(m0 + ar0) * K + kt) * 2 + kb, (char*)As + c0 * 1024);
    GLOAD16(Ac + ((size_t)(m0 + ar1) * K + kt) * 2 + kb, (char*)As + c1 * 1024);
    GLOAD16(Bc + ((size_t)(n0 + ar0) * K + kt) * 2 + kb, (char*)Bs + c0 * 1024);
    GLOAD16(Bc + ((size_t)(n0 + ar1) * K + kt) * 2 + kb, (char*)Bs + c1 * 1024);
    __syncthreads();
    short8 af[4], bfv[4];
    #pragma unroll
    for (int mi = 0; mi < 4; mi++)
      af[mi] = *(const short8a*)&As[(wr * 64 + mi * 16 + lr) * 32 + kg * 8];
    #pragma unroll
    for (int ni = 0; ni < 4; ni++)
      bfv[ni] = *(const short8a*)&Bs[(wc * 64 + ni * 16 + lr) * 32 + kg * 8];
    #pragma unroll
    for (int mi = 0; mi < 4; mi++)
      #pragma unroll
      for (int ni = 0; ni < 4; ni++)
        acc[mi][ni] = __builtin_amdgcn_mfma_f32_16x16x32_bf16(af[mi], bfv[ni], acc[mi][ni], 0, 0, 0);
    __syncthreads();
  }
  #pragma unroll
  for (int mi = 0; mi < 4; mi++) {
    #pragma unroll
    for (int ni = 0; ni < 4; ni++) {
      int col = n0 + wc * 64 + ni * 16 + lr;
      #pragma unroll
      for (int r = 0; r < 4; r++) {
        int row = m0 + wr * 64 + mi * 16 + kg * 4 + r;  // C/D: col=lane&15, row=(lane>>4)*4+r
        float v = acc[mi][ni][r];
        if (bias) v += bias[row];
        if (Cf) Cf[(size_t)row * N + col] = v;
        else    Cb[(size_t)row * N + col] = f2bf(v);
      }
    }
  }
}

// ---------------- RoPE + transpose: in (nH*D, S) bf16 -> out (nH, S, D) bf16 ----------------
__global__ __launch_bounds__(256) void rope_transpose_kernel(const u16* __restrict__ in,
                                                             u16* __restrict__ out,
                                                             const float* __restrict__ cp,
                                                             const float* __restrict__ sp) {
  __shared__ u16 t[128][33];
  int h = blockIdx.x;
  int s0 = blockIdx.y * 32;
  int tid = threadIdx.x;
  #pragma unroll
  for (int i = 0; i < 16; i++) {
    int idx = tid + i * 256;
    int row = idx >> 5, sc = idx & 31;
    t[row][sc] = in[(size_t)(h * 128 + row) * S_ + s0 + sc];
  }
  __syncthreads();
  int d = tid & 127, sh = tid >> 7;
  int dl = d & 63;
  bool hi = d >= 64;
  #pragma unroll
  for (int j = 0; j < 16; j++) {
    int sl = sh * 16 + j;
    int s = s0 + sl;
    float x = bf2f(t[d][sl]);
    float p = bf2f(t[d ^ 64][sl]);          // rotate partner
    float c  = cp[(size_t)s * D_ + dl];     // cos[s,d] == cos[s,d&63]
    float sn = sp[(size_t)s * D_ + dl];
    float o = hi ? fmaf(p, sn, x * c) : fmaf(-p, sn, x * c);
    out[((size_t)h * S_ + s) * D_ + d] = f2bf(o);
  }
}

// ---------------- flash attention (causal GQA) ----------------
// Q (H,S,D), K (KV,S,D), V (KV*D,S) all bf16; Ot (S, H*D) bf16 (= B^T for final GEMM).
__global__ __launch_bounds__(256) void attn_kernel(const u16* __restrict__ Q, const u16* __restrict__ K,
                                                   const u16* __restrict__ V, u16* __restrict__ Ot) {
  __shared__ alignas(16) u16 Plds[4][16][32];  // per-wave P tile
  int h = blockIdx.x, qt = blockIdx.y;
  int kv = h >> 2;                              // G = 4
  int tid = threadIdx.x, wid = tid >> 6, lane = tid & 63;
  int lr = lane & 15, kg = lane >> 4;
  int q0 = qt * 64 + wid * 16;                  // this wave's 16 query rows
  const u16* Qb = Q + ((size_t)h * S_ + q0) * D_;
  const u16* Kb = K + (size_t)kv * S_ * D_;
  const u16* Vb = V + (size_t)kv * D_ * S_;
  short8 qf[4];
  #pragma unroll
  for (int kk = 0; kk < 4; kk++)
    qf[kk] = *(const short8a*)(Qb + (size_t)lr * D_ + kk * 32 + kg * 8);
  f32x4 acc[8] = {};
  float m[4], ls[4];
  #pragma unroll
  for (int r = 0; r < 4; r++) { m[r] = -1e30f; ls[r] = 0.f; }
  const float scale = 0.08838834764831843f;     // 1/sqrt(128)
  int nlt = qt * 2 + 2;                          // causal bound for the block
  for (int lt = 0; lt < nlt; lt++) {
    int l0 = lt * 32;
    f32x4 st0 = {}, st1 = {};
    #pragma unroll
    for (int kk = 0; kk < 4; kk++) {             // S^T[s][l] = sum_d Q[s,d] K[l,d]
      short8 kf0 = *(const short8a*)(Kb + (size_t)(l0 + lr) * D_ + kk * 32 + kg * 8);
      short8 kf1 = *(const short8a*)(Kb + (size_t)(l0 + 16 + lr) * D_ + kk * 32 + kg * 8);
      st0 = __builtin_amdgcn_mfma_f32_16x16x32_bf16(qf[kk], kf0, st0, 0, 0, 0);
      st1 = __builtin_amdgcn_mfma_f32_16x16x32_bf16(qf[kk], kf1, st1, 0, 0, 0);
    }
    int la0 = l0 + lr, la1 = l0 + 16 + lr;
    #pragma unroll
    for (int r = 0; r < 4; r++) {
      int sa = q0 + kg * 4 + r;
      float v0 = (la0 <= sa) ? st0[r] * scale : -1e30f;   // causal mask
      float v1 = (la1 <= sa) ? st1[r] * scale : -1e30f;
      float mx = fmaxf(v0, v1);
      #pragma unroll
      for (int x = 1; x < 16; x <<= 1) mx = fmaxf(mx, __shfl_xor(mx, x, 64));
      float mn = fmaxf(m[r], mx);
      float e0 = __expf(v0 - mn), e1 = __expf(v1 - mn);
      float f = __expf(m[r] - mn);
      float rs = e0 + e1;
      #pragma unroll
      for (int x = 1; x < 16; x <<= 1) rs += __shfl_xor(rs, x, 64);
      ls[r] = ls[r] * f + rs;
      m[r] = mn;
      #pragma unroll
      for (int dc = 0; dc < 8; dc++) acc[dc][r] *= f;
      Plds[wid][kg * 4 + r][lr] = f2bf(e0);      // P in [s][l] layout
      Plds[wid][kg * 4 + r][16 + lr] = f2bf(e1);
    }
    // same-wave LDS ops are in-order; no barrier needed (per-wave buffer)
    short8 pf = *(const short8a*)&Plds[wid][lr][kg * 8];   // A-frag: row=s, k=l
    #pragma unroll
    for (int dc = 0; dc < 8; dc++) {
      short8 vf = *(const short8a*)(Vb + (size_t)(dc * 16 + lr) * S_ + l0 + kg * 8);
      acc[dc] = __builtin_amdgcn_mfma_f32_16x16x32_bf16(pf, vf, acc[dc], 0, 0, 0);
    }
  }
  #pragma unroll
  for (int dc = 0; dc < 8; dc++) {
    #pragma unroll
    for (int r = 0; r < 4; r++) {
      float val = acc[dc][r] / ls[r];
      int s = q0 + kg * 4 + r;
      Ot[(size_t)s * HID_ + h * D_ + dc * 16 + lr] = f2bf(val);
    }
  }
}

// ---------------- workspace layout (bytes) ----------------
static constexpr size_t OFF_WQ = 0;            // 33554432  (later reused as Q_att 16.8MB)
static constexpr size_t OFF_WK = 33554432;     //  8388608  (later reused as K_att 4.2MB)
static constexpr size_t OFF_WV = 41943040;     //  8388608
static constexpr size_t OFF_WO = 50331648;     // 33554432
static constexpr size_t OFF_XT = 83886080;     // 16777216
static constexpr size_t OFF_QT = 100663296;    // 16777216  (later reused as O^T 16.8MB)
static constexpr size_t OFF_KT = 117440512;    //  4194304
static constexpr size_t OFF_VB = 121634816;    //  4194304  -> total 125829120 B

extern "C" void kernel_launch(void* const* d_in, const int* in_sizes, int n_in,
                              void* d_out, int out_size, void* d_ws, size_t ws_size,
                              hipStream_t stream) {
  const float* x    = (const float*)d_in[0];
  const float* wq   = (const float*)d_in[1];
  const float* bq   = (const float*)d_in[2];
  const float* wk   = (const float*)d_in[3];
  const float* bk   = (const float*)d_in[4];
  const float* wv   = (const float*)d_in[5];
  const float* bv   = (const float*)d_in[6];
  const float* wo   = (const float*)d_in[7];
  const float* cosP = (const float*)d_in[8];
  const float* sinP = (const float*)d_in[9];
  char* ws = (char*)d_ws;
  u16* WQ = (u16*)(ws + OFF_WQ);
  u16* WK = (u16*)(ws + OFF_WK);
  u16* WV = (u16*)(ws + OFF_WV);
  u16* WO = (u16*)(ws + OFF_WO);
  u16* XT = (u16*)(ws + OFF_XT);
  u16* QT = (u16*)(ws + OFF_QT);
  u16* KT = (u16*)(ws + OFF_KT);
  u16* VB = (u16*)(ws + OFF_VB);
  u16* QATT = (u16*)(ws + OFF_WQ);   // reuse: wq dead after QKV gemms
  u16* KATT = (u16*)(ws + OFF_WK);
  u16* OT   = (u16*)(ws + OFF_QT);   // reuse: q_tmp dead after rope
  float* y = (float*)d_out;

  // 1) casts
  cast_kernel<<<2048, 256, 0, stream>>>(wq, WQ, (HID_ * HID_) / 4);
  cast_kernel<<<2048, 256, 0, stream>>>(wk, WK, (KV_ * D_ * HID_) / 4);
  cast_kernel<<<2048, 256, 0, stream>>>(wv, WV, (KV_ * D_ * HID_) / 4);
  cast_kernel<<<2048, 256, 0, stream>>>(wo, WO, (HID_ * HID_) / 4);
  // 2) X^T
  transpose_cast_kernel<<<dim3(S_ / 32, HID_ / 32), 256, 0, stream>>>(x, XT);
  // 3) QKV projections (bias fused, bf16 out)
  gemm_bt<<<dim3(S_ / 128, HID_ / 128), 256, 0, stream>>>(WQ, XT, bq, QT, nullptr, HID_, S_, HID_);
  gemm_bt<<<dim3(S_ / 128, (KV_ * D_) / 128), 256, 0, stream>>>(WK, XT, bk, KT, nullptr, KV_ * D_, S_, HID_);
  gemm_bt<<<dim3(S_ / 128, (KV_ * D_) / 128), 256, 0, stream>>>(WV, XT, bv, VB, nullptr, KV_ * D_, S_, HID_);
  // 4) RoPE + transpose to attention layouts
  rope_transpose_kernel<<<dim3(H_, S_ / 32), 256, 0, stream>>>(QT, QATT, cosP, sinP);
  rope_transpose_kernel<<<dim3(KV_, S_ / 32), 256, 0, stream>>>(KT, KATT, cosP, sinP);
  // 5) causal GQA flash attention -> O^T (S, H*D)
  attn_kernel<<<dim3(H_, S_ / 64), 256, 0, stream>>>(QATT, KATT, VB, OT);
  // 6) output projection -> fp32 d_out
  gemm_bt<<<dim3(S_ / 128, HID_ / 128), 256, 0, stream>>>(WO, OT, nullptr, nullptr, y, HID_, S_, HID_);
}

// Round 2
// 577.755 us; speedup vs baseline: 1.3354x; 1.3354x over previous
//
#include <hip/hip_runtime.h>
#include <hip/hip_bf16.h>

// Problem constants
#define H_   32
#define KV_  8
#define D_   128
#define S_   2048
#define HID_ 4096

typedef __attribute__((ext_vector_type(8))) short short8;
typedef short8 short8a __attribute__((may_alias));
typedef __attribute__((ext_vector_type(4))) float f32x4;
typedef unsigned short u16;
typedef unsigned int u32;

__device__ __forceinline__ u16 f2bf(float f) {
  union { float f; unsigned u; } a; a.f = f;
  unsigned r = a.u + 0x7fffu + ((a.u >> 16) & 1u);   // RNE
  return (u16)(r >> 16);
}
__device__ __forceinline__ float bf2f(u16 h) {
  union { unsigned u; float f; } a; a.u = ((unsigned)h) << 16;
  return a.f;
}

#define GLOAD16(g, l) __builtin_amdgcn_global_load_lds( \
    (const __attribute__((address_space(1))) void*)(g), \
    (__attribute__((address_space(3))) void*)(l), 16, 0, 0)

// ---------------- elementwise fp32 -> bf16 cast ----------------
__global__ void cast_kernel(const float* __restrict__ in, u16* __restrict__ out, int n4) {
  int i = blockIdx.x * blockDim.x + threadIdx.x;
  int stride = gridDim.x * blockDim.x;
  for (; i < n4; i += stride) {
    float4 v = ((const float4*)in)[i];
    ushort4 o;
    o.x = f2bf(v.x); o.y = f2bf(v.y); o.z = f2bf(v.z); o.w = f2bf(v.w);
    ((ushort4*)out)[i] = o;
  }
}

// ---------------- X (HID,S) fp32 -> X^T (S,HID) bf16 ----------------
__global__ __launch_bounds__(256) void transpose_cast_kernel(const float* __restrict__ in,
                                                             u16* __restrict__ out) {
  __shared__ float t[32][33];
  int tx = threadIdx.x & 31, ty = threadIdx.x >> 5;  // 32x8
  int s0 = blockIdx.x * 32, c0 = blockIdx.y * 32;
  #pragma unroll
  for (int i = 0; i < 4; i++)
    t[ty + i * 8][tx] = in[(size_t)(c0 + ty + i * 8) * S_ + s0 + tx];
  __syncthreads();
  #pragma unroll
  for (int i = 0; i < 4; i++)
    out[(size_t)(s0 + ty + i * 8) * HID_ + c0 + tx] = f2bf(t[tx][ty + i * 8]);
}

// ---------------- bf16 GEMM: C(MxN) = A(MxK) * Bt(NxK)^T (+bias) ----------------
__global__ __launch_bounds__(256) void gemm_bt(const u16* __restrict__ A, const u16* __restrict__ Bt,
                                               const float* __restrict__ bias,
                                               u16* __restrict__ Cb, float* __restrict__ Cf,
                                               int M, int N, int K) {
  __shared__ alignas(16) u16 As[128 * 32];
  __shared__ alignas(16) u16 Bs[128 * 32];
  int tid = threadIdx.x, wid = tid >> 6, lane = tid & 63;
  int lr = lane & 15, kg = lane >> 4;
  int m0 = blockIdx.y * 128, n0 = blockIdx.x * 128;
  int wr = wid >> 1, wc = wid & 1;
  f32x4 acc[4][4] = {};
  int c0 = wid * 2, c1 = wid * 2 + 1;
  int ar0 = c0 * 16 + (lane >> 2);
  int ar1 = c1 * 16 + (lane >> 2);
  int kb = (lane & 3) * 16;
  const char* Ac = (const char*)A;
  const char* Bc = (const char*)Bt;
  for (int kt = 0; kt < K; kt += 32) {
    GLOAD16(Ac + ((size_t)(m0 + ar0) * K + kt) * 2 + kb, (char*)As + c0 * 1024);
    GLOAD16(Ac + ((size_t)(m0 + ar1) * K + kt) * 2 + kb, (char*)As + c1 * 1024);
    GLOAD16(Bc + ((size_t)(n0 + ar0) * K + kt) * 2 + kb, (char*)Bs + c0 * 1024);
    GLOAD16(Bc + ((size_t)(n0 + ar1) * K + kt) * 2 + kb, (char*)Bs + c1 * 1024);
    __syncthreads();
    short8 af[4], bfv[4];
    #pragma unroll
    for (int mi = 0; mi < 4; mi++)
      af[mi] = *(const short8a*)&As[(wr * 64 + mi * 16 + lr) * 32 + kg * 8];
    #pragma unroll
    for (int ni = 0; ni < 4; ni++)
      bfv[ni] = *(const short8a*)&Bs[(wc * 64 + ni * 16 + lr) * 32 + kg * 8];
    #pragma unroll
    for (int mi = 0; mi < 4; mi++)
      #pragma unroll
      for (int ni = 0; ni < 4; ni++)
        acc[mi][ni] = __builtin_amdgcn_mfma_f32_16x16x32_bf16(af[mi], bfv[ni], acc[mi][ni], 0, 0, 0);
    __syncthreads();
  }
  #pragma unroll
  for (int mi = 0; mi < 4; mi++) {
    #pragma unroll
    for (int ni = 0; ni < 4; ni++) {
      int col = n0 + wc * 64 + ni * 16 + lr;
      #pragma unroll
      for (int r = 0; r < 4; r++) {
        int row = m0 + wr * 64 + mi * 16 + kg * 4 + r;
        float v = acc[mi][ni][r];
        if (bias) v += bias[row];
        if (Cf) Cf[(size_t)row * N + col] = v;
        else    Cb[(size_t)row * N + col] = f2bf(v);
      }
    }
  }
}

// ---------------- RoPE + transpose: in (nH*D, S) bf16 -> out (nH, S, D) bf16 ----------------
__global__ __launch_bounds__(256) void rope_transpose_kernel(const u16* __restrict__ in,
                                                             u16* __restrict__ out,
                                                             const float* __restrict__ cp,
                                                             const float* __restrict__ sp,
                                                             float oscale) {
  __shared__ u16 t[128][33];
  int h = blockIdx.x;
  int s0 = blockIdx.y * 32;
  int tid = threadIdx.x;
  #pragma unroll
  for (int i = 0; i < 16; i++) {
    int idx = tid + i * 256;
    int row = idx >> 5, sc = idx & 31;
    t[row][sc] = in[(size_t)(h * 128 + row) * S_ + s0 + sc];
  }
  __syncthreads();
  int d = tid & 127, sh = tid >> 7;
  int dl = d & 63;
  bool hi = d >= 64;
  #pragma unroll
  for (int j = 0; j < 16; j++) {
    int sl = sh * 16 + j;
    int s = s0 + sl;
    float x = bf2f(t[d][sl]);
    float p = bf2f(t[d ^ 64][sl]);
    float c  = cp[(size_t)s * D_ + dl];
    float sn = sp[(size_t)s * D_ + dl];
    float o = hi ? fmaf(p, sn, x * c) : fmaf(-p, sn, x * c);
    out[((size_t)h * S_ + s) * D_ + d] = f2bf(o * oscale);
  }
}

// ---------------- flash attention v2 (causal GQA, swapped-QK, staged KV) ----------------
// Q (H,S,D) bf16 PRE-SCALED by log2(e)/sqrt(D); K (KV,S,D) bf16; V (KV*D,S) bf16.
// Out: Ot (S, H*D) bf16.
// Block: 4 waves x 32 q-rows = 128 q. Grid (H, S/128), heavy qtile first.
__global__ __launch_bounds__(256) void attn_v2(const u16* __restrict__ Q, const u16* __restrict__ K,
                                               const u16* __restrict__ V, u16* __restrict__ Ot) {
  __shared__ alignas(16) u16 Ks[2][64 * 128];   // [l][d], XOR-swizzled rows
  __shared__ alignas(16) u16 Vs[2][128 * 64];   // [d][l], XOR-swizzled rows
  __shared__ alignas(16) u16 Pl[4][2][16 * 64]; // per-wave per-mgroup P, swizzled
  int h = blockIdx.x;
  int qtile = (int)(gridDim.y - 1) - (int)blockIdx.y;   // heavy first
  int kv = h >> 2;
  int tid = threadIdx.x, wid = tid >> 6, lane = tid & 63;
  int lr = lane & 15, kg = lane >> 4;
  int q0w = qtile * 128 + wid * 32;
  const u16* Qb = Q + ((size_t)h * S_ + q0w) * D_;
  const u16* Kb = K + (size_t)kv * S_ * D_;
  const u16* Vb = V + (size_t)kv * D_ * S_;
  int sw = (lr & 7) << 3;   // element-granularity XOR swizzle for this lane's rows

  short8 qf[2][4];
  #pragma unroll
  for (int m = 0; m < 2; m++)
    #pragma unroll
    for (int kk = 0; kk < 4; kk++)
      qf[m][kk] = *(const short8a*)(Qb + (size_t)(m * 16 + lr) * D_ + kk * 32 + kg * 8);

  f32x4 acc[2][8] = {};
  float mreg[2] = {-1e30f, -1e30f};
  float lsum[2] = {0.f, 0.f};

  // staging lane constants (linear LDS dest, inverse-swizzled global source)
  int krow[4], kcb[4], vrow[4], vcb[4];
  #pragma unroll
  for (int j = 0; j < 4; j++) {
    int c = wid * 4 + j;
    int o = c * 1024 + lane * 16;
    krow[j] = o >> 8;
    kcb[j] = (o & 255) ^ ((krow[j] & 7) << 4);
    vrow[j] = o >> 7;
    vcb[j] = (o & 127) ^ ((vrow[j] & 7) << 4);
  }

  int nlt = 2 * qtile + 2;
  // prologue stage tile 0
  #pragma unroll
  for (int j = 0; j < 4; j++) {
    int c = wid * 4 + j;
    GLOAD16((const char*)Kb + ((size_t)krow[j] * D_) * 2 + kcb[j], (char*)Ks[0] + c * 1024);
    GLOAD16((const char*)Vb + ((size_t)vrow[j] * S_) * 2 + vcb[j], (char*)Vs[0] + c * 1024);
  }
  int cur = 0;
  for (int t = 0; t < nlt; t++) {
    __syncthreads();    // buf[cur] staged & visible
    if (t + 1 < nlt) {
      int l1 = (t + 1) * 64;
      #pragma unroll
      for (int j = 0; j < 4; j++) {
        int c = wid * 4 + j;
        GLOAD16((const char*)Kb + ((size_t)(l1 + krow[j]) * D_) * 2 + kcb[j],
                (char*)Ks[cur ^ 1] + c * 1024);
        GLOAD16((const char*)Vb + ((size_t)vrow[j] * S_ + l1) * 2 + vcb[j],
                (char*)Vs[cur ^ 1] + c * 1024);
      }
    }
    int l0 = t * 64;
    bool act0 = l0 <= q0w + 15;
    bool act1 = l0 <= q0w + 31;
    if (act1) {
      const u16* Kc = Ks[cur];
      const u16* Vc = Vs[cur];
      // ---- QK^T (swapped: K as A, Q as B -> S^T[l][q]) ----
      f32x4 st[2][4] = {};
      #pragma unroll
      for (int ls = 0; ls < 4; ls++) {
        short8 kf[4];
        #pragma unroll
        for (int kk = 0; kk < 4; kk++)
          kf[kk] = *(const short8a*)&Kc[(ls * 16 + lr) * 128 + ((kk * 32 + kg * 8) ^ sw)];
        #pragma unroll
        for (int kk = 0; kk < 4; kk++) {
          st[0][ls] = __builtin_amdgcn_mfma_f32_16x16x32_bf16(kf[kk], qf[0][kk], st[0][ls], 0, 0, 0);
          st[1][ls] = __builtin_amdgcn_mfma_f32_16x16x32_bf16(kf[kk], qf[1][kk], st[1][ls], 0, 0, 0);
        }
      }
      // ---- online softmax per m-group (lane owns q-row lr; l in-lane) ----
      #pragma unroll
      for (int m = 0; m < 2; m++) {
        bool act = m ? act1 : act0;
        if (!act) continue;
        int qrow = q0w + m * 16 + lr;
        if (l0 + 63 > q0w + m * 16) {     // diagonal: mask l > q
          #pragma unroll
          for (int ls = 0; ls < 4; ls++)
            #pragma unroll
            for (int r = 0; r < 4; r++) {
              int l = l0 + ls * 16 + kg * 4 + r;
              st[m][ls][r] = (l <= qrow) ? st[m][ls][r] : -1e30f;
            }
        }
        // row max: in-lane 16 + 2 shfl (kg groups)
        float rmax;
        {
          float a0 = fmaxf(fmaxf(st[m][0][0], st[m][0][1]), fmaxf(st[m][0][2], st[m][0][3]));
          float a1 = fmaxf(fmaxf(st[m][1][0], st[m][1][1]), fmaxf(st[m][1][2], st[m][1][3]));
          float a2 = fmaxf(fmaxf(st[m][2][0], st[m][2][1]), fmaxf(st[m][2][2], st[m][2][3]));
          float a3 = fmaxf(fmaxf(st[m][3][0], st[m][3][1]), fmaxf(st[m][3][2], st[m][3][3]));
          rmax = fmaxf(fmaxf(a0, a1), fmaxf(a2, a3));
        }
        rmax = fmaxf(rmax, __shfl_xor(rmax, 16, 64));
        rmax = fmaxf(rmax, __shfl_xor(rmax, 32, 64));
        if (__any(rmax > mreg[m] + 8.0f)) {        // T13 defer-rescale
          float nm = fmaxf(mreg[m], rmax);
          float f = __builtin_amdgcn_exp2f(mreg[m] - nm);
          mreg[m] = nm;
          lsum[m] *= f;
          float fr0 = __shfl(f, kg * 4 + 0, 64);
          float fr1 = __shfl(f, kg * 4 + 1, 64);
          float fr2 = __shfl(f, kg * 4 + 2, 64);
          float fr3 = __shfl(f, kg * 4 + 3, 64);
          #pragma unroll
          for (int dc = 0; dc < 8; dc++) {
            acc[m][dc][0] *= fr0; acc[m][dc][1] *= fr1;
            acc[m][dc][2] *= fr2; acc[m][dc][3] *= fr3;
          }
        }
        float e[4][4];
        #pragma unroll
        for (int ls = 0; ls < 4; ls++)
          #pragma unroll
          for (int r = 0; r < 4; r++)
            e[ls][r] = __builtin_amdgcn_exp2f(st[m][ls][r] - mreg[m]);
        float rs = 0.f;
        #pragma unroll
        for (int ls = 0; ls < 4; ls++)
          rs += (e[ls][0] + e[ls][1]) + (e[ls][2] + e[ls][3]);
        rs += __shfl_xor(rs, 16, 64);
        rs += __shfl_xor(rs, 32, 64);
        lsum[m] += rs;
        // pack P -> LDS (4x b64 writes, swizzled)
        u16* Pw = &Pl[wid][m][0];
        #pragma unroll
        for (int ls = 0; ls < 4; ls++) {
          __hip_bfloat162 p01 = __float22bfloat162_rn(float2{e[ls][0], e[ls][1]});
          __hip_bfloat162 p23 = __float22bfloat162_rn(float2{e[ls][2], e[ls][3]});
          uint2 pk;
          pk.x = *(u32*)&p01;
          pk.y = *(u32*)&p23;
          *(uint2*)&Pw[lr * 64 + ((ls * 16 + kg * 4) ^ sw)] = pk;
        }
      }
      // ---- PV ----
      #pragma unroll
      for (int kk = 0; kk < 2; kk++) {
        short8 pf0 = {}, pf1;
        if (act0) pf0 = *(const short8a*)&Pl[wid][0][lr * 64 + ((kk * 32 + kg * 8) ^ sw)];
        pf1 = *(const short8a*)&Pl[wid][1][lr * 64 + ((kk * 32 + kg * 8) ^ sw)];
        #pragma unroll
        for (int dc = 0; dc < 8; dc++) {
          short8 vf = *(const short8a*)&Vc[(dc * 16 + lr) * 64 + ((kk * 32 + kg * 8) ^ sw)];
          if (act0) acc[0][dc] = __builtin_amdgcn_mfma_f32_16x16x32_bf16(pf0, vf, acc[0][dc], 0, 0, 0);
          acc[1][dc] = __builtin_amdgcn_mfma_f32_16x16x32_bf16(pf1, vf, acc[1][dc], 0, 0, 0);
        }
      }
    }
    cur ^= 1;
  }
  // ---- epilogue: normalize & store O^T ----
  #pragma unroll
  for (int m = 0; m < 2; m++) {
    float inv0 = 1.0f / __shfl(lsum[m], kg * 4 + 0, 64);
    float inv1 = 1.0f / __shfl(lsum[m], kg * 4 + 1, 64);
    float inv2 = 1.0f / __shfl(lsum[m], kg * 4 + 2, 64);
    float inv3 = 1.0f / __shfl(lsum[m], kg * 4 + 3, 64);
    #pragma unroll
    for (int dc = 0; dc < 8; dc++) {
      int col = h * D_ + dc * 16 + lr;
      int qg = q0w + m * 16 + kg * 4;
      Ot[(size_t)(qg + 0) * HID_ + col] = f2bf(acc[m][dc][0] * inv0);
      Ot[(size_t)(qg + 1) * HID_ + col] = f2bf(acc[m][dc][1] * inv1);
      Ot[(size_t)(qg + 2) * HID_ + col] = f2bf(acc[m][dc][2] * inv2);
      Ot[(size_t)(qg + 3) * HID_ + col] = f2bf(acc[m][dc][3] * inv3);
    }
  }
}

// ---------------- workspace layout (bytes) ----------------
static constexpr size_t OFF_WQ = 0;            // 33554432  (later reused as Q_att 16.8MB)
static constexpr size_t OFF_WK = 33554432;     //  8388608  (later reused as K_att 4.2MB)
static constexpr size_t OFF_WV = 41943040;     //  8388608
static constexpr size_t OFF_WO = 50331648;     // 33554432
static constexpr size_t OFF_XT = 83886080;     // 16777216
static constexpr size_t OFF_QT = 100663296;    // 16777216  (later reused as O^T 16.8MB)
static constexpr size_t OFF_KT = 117440512;    //  4194304
static constexpr size_t OFF_VB = 121634816;    //  4194304  -> total 125829120 B

// log2(e)/sqrt(128): folds softmax scale + base-2 exp into Q
#define QSCALE 0.1275176329533421f

extern "C" void kernel_launch(void* const* d_in, const int* in_sizes, int n_in,
                              void* d_out, int out_size, void* d_ws, size_t ws_size,
                              hipStream_t stream) {
  const float* x    = (const float*)d_in[0];
  const float* wq   = (const float*)d_in[1];
  const float* bq   = (const float*)d_in[2];
  const float* wk   = (const float*)d_in[3];
  const float* bk   = (const float*)d_in[4];
  const float* wv   = (const float*)d_in[5];
  const float* bv   = (const float*)d_in[6];
  const float* wo   = (const float*)d_in[7];
  const float* cosP = (const float*)d_in[8];
  const float* sinP = (const float*)d_in[9];
  char* ws = (char*)d_ws;
  u16* WQ = (u16*)(ws + OFF_WQ);
  u16* WK = (u16*)(ws + OFF_WK);
  u16* WV = (u16*)(ws + OFF_WV);
  u16* WO = (u16*)(ws + OFF_WO);
  u16* XT = (u16*)(ws + OFF_XT);
  u16* QT = (u16*)(ws + OFF_QT);
  u16* KT = (u16*)(ws + OFF_KT);
  u16* VB = (u16*)(ws + OFF_VB);
  u16* QATT = (u16*)(ws + OFF_WQ);   // reuse: wq dead after QKV gemms
  u16* KATT = (u16*)(ws + OFF_WK);
  u16* OT   = (u16*)(ws + OFF_QT);   // reuse: q_tmp dead after rope
  float* y = (float*)d_out;

  // 1) casts
  cast_kernel<<<2048, 256, 0, stream>>>(wq, WQ, (HID_ * HID_) / 4);
  cast_kernel<<<2048, 256, 0, stream>>>(wk, WK, (KV_ * D_ * HID_) / 4);
  cast_kernel<<<2048, 256, 0, stream>>>(wv, WV, (KV_ * D_ * HID_) / 4);
  cast_kernel<<<2048, 256, 0, stream>>>(wo, WO, (HID_ * HID_) / 4);
  // 2) X^T
  transpose_cast_kernel<<<dim3(S_ / 32, HID_ / 32), 256, 0, stream>>>(x, XT);
  // 3) QKV projections (bias fused, bf16 out)
  gemm_bt<<<dim3(S_ / 128, HID_ / 128), 256, 0, stream>>>(WQ, XT, bq, QT, nullptr, HID_, S_, HID_);
  gemm_bt<<<dim3(S_ / 128, (KV_ * D_) / 128), 256, 0, stream>>>(WK, XT, bk, KT, nullptr, KV_ * D_, S_, HID_);
  gemm_bt<<<dim3(S_ / 128, (KV_ * D_) / 128), 256, 0, stream>>>(WV, XT, bv, VB, nullptr, KV_ * D_, S_, HID_);
  // 4) RoPE + transpose to attention layouts (Q pre-scaled by log2e/sqrt(D))
  rope_transpose_kernel<<<dim3(H_, S_ / 32), 256, 0, stream>>>(QT, QATT, cosP, sinP, QSCALE);
  rope_transpose_kernel<<<dim3(KV_, S_ / 32), 256, 0, stream>>>(KT, KATT, cosP, sinP, 1.0f);
  // 5) causal GQA flash attention -> O^T (S, H*D)
  attn_v2<<<dim3(H_, S_ / 128), 256, 0, stream>>>(QATT, KATT, VB, OT);
  // 6) output projection -> fp32 d_out
  gemm_bt<<<dim3(S_ / 128, HID_ / 128), 256, 0, stream>>>(WO, OT, nullptr, nullptr, y, HID_, S_, HID_);
}

// Round 3
// 427.904 us; speedup vs baseline: 1.8031x; 1.3502x over previous
//
#include <hip/hip_runtime.h>
#include <hip/hip_bf16.h>

// Problem constants
#define H_   32
#define KV_  8
#define D_   128
#define S_   2048
#define HID_ 4096

typedef __attribute__((ext_vector_type(8))) short short8;
typedef short8 short8a __attribute__((may_alias));
typedef __attribute__((ext_vector_type(4))) float f32x4;
typedef unsigned short u16;
typedef unsigned int u32;

__device__ __forceinline__ u16 f2bf(float f) {
  union { float f; unsigned u; } a; a.f = f;
  unsigned r = a.u + 0x7fffu + ((a.u >> 16) & 1u);   // RNE
  return (u16)(r >> 16);
}
__device__ __forceinline__ float bf2f(u16 h) {
  union { unsigned u; float f; } a; a.u = ((unsigned)h) << 16;
  return a.f;
}

#define GLOAD16(g, l) __builtin_amdgcn_global_load_lds( \
    (const __attribute__((address_space(1))) void*)(g), \
    (__attribute__((address_space(3))) void*)(l), 16, 0, 0)

// ---------------- fused fp32 -> bf16 cast of all 4 weights ----------------
__global__ void cast4_kernel(const float* __restrict__ s0, const float* __restrict__ s1,
                             const float* __restrict__ s2, const float* __restrict__ s3,
                             u16* __restrict__ d0, u16* __restrict__ d1,
                             u16* __restrict__ d2, u16* __restrict__ d3,
                             int n0, int n1, int n2, int n3) {
  int total = n0 + n1 + n2 + n3;
  for (int i = blockIdx.x * blockDim.x + threadIdx.x; i < total; i += gridDim.x * blockDim.x) {
    const float* s; u16* d; int k = i;
    if (k < n0) { s = s0; d = d0; }
    else if ((k -= n0) < n1) { s = s1; d = d1; }
    else if ((k -= n1) < n2) { s = s2; d = d2; }
    else { k -= n2; s = s3; d = d3; }
    float4 v = ((const float4*)s)[k];
    ushort4 o;
    o.x = f2bf(v.x); o.y = f2bf(v.y); o.z = f2bf(v.z); o.w = f2bf(v.w);
    ((ushort4*)d)[k] = o;
  }
}

// ---------------- X (HID,S) fp32 -> X^T (S,HID) bf16 ----------------
__global__ __launch_bounds__(256) void transpose_cast_kernel(const float* __restrict__ in,
                                                             u16* __restrict__ out) {
  __shared__ float t[32][33];
  int tx = threadIdx.x & 31, ty = threadIdx.x >> 5;  // 32x8
  int s0 = blockIdx.x * 32, c0 = blockIdx.y * 32;
  #pragma unroll
  for (int i = 0; i < 4; i++)
    t[ty + i * 8][tx] = in[(size_t)(c0 + ty + i * 8) * S_ + s0 + tx];
  __syncthreads();
  #pragma unroll
  for (int i = 0; i < 4; i++)
    out[(size_t)(s0 + ty + i * 8) * HID_ + c0 + tx] = f2bf(t[tx][ty + i * 8]);
}

// ---------------- 256x256 8-phase bf16 GEMM: C(MxN) = A(MxK) * Bt(NxK)^T ----------------
// A,Bt row-major K-contiguous bf16. 8 waves (512 thr), BK=64, 128KB LDS,
// XOR-swizzled LDS (involution on 16B granules), counted vmcnt(4) at ph4/ph8,
// setprio around MFMA clusters, bijective XCD swizzle.
__device__ __forceinline__ short8 ldsfrag(const u16* slot, int row, int ks, int kg) {
  int cb = (ks * 64 + kg * 16) ^ ((row & 7) << 4);
  return *(const short8a*)((const char*)slot + row * 128 + cb);
}

__global__ __launch_bounds__(512, 2) void gemm256(const u16* __restrict__ A, const u16* __restrict__ Bt,
    const float* __restrict__ bq, const float* __restrict__ bk, const float* __restrict__ bv,
    u16* __restrict__ Cb, float* __restrict__ Cf, int M, int N, int K) {
  __shared__ alignas(16) u16 Asl[4][8192];   // 4 half-slots (tile-parity x half): 64KB
  __shared__ alignas(16) u16 Bsl[4][8192];   // 64KB
  int tid = threadIdx.x, wid = tid >> 6, lane = tid & 63;
  int lr = lane & 15, kg = lane >> 4;
  // bijective XCD swizzle (m204)
  int gx = gridDim.x, nwg = gx * gridDim.y;
  int lid = blockIdx.y * gx + blockIdx.x;
  int q = nwg >> 3, r = nwg & 7;
  int xcd = lid & 7, idx = lid >> 3;
  int swz = (xcd < r ? xcd * (q + 1) : r * (q + 1) + (xcd - r) * q) + idx;
  int m0 = (swz / gx) * 256, n0 = (swz % gx) * 256;
  const u16* Ap = A + (size_t)m0 * K;
  const u16* Bp = Bt + (size_t)n0 * K;
  int wrow = (wid >> 2) * 64, wcol = (wid & 3) * 32;
  f32x4 acc[2][2][4][2] = {};
  int NT = K >> 6;

  auto STAGE = [&](const u16* gp, int tile, int half, u16* slot) {
    #pragma unroll
    for (int j = 0; j < 2; j++) {
      int p = j * 8192 + tid * 16;          // linear byte pos in 16KB half
      int row = p >> 7, cb = p & 127;
      int gcb = cb ^ ((row & 7) << 4);      // inverse-swizzled global source
      const char* src = (const char*)gp + ((size_t)(half * 128 + row) * K + tile * 64) * 2 + gcb;
      char* dst = (char*)slot + j * 8192 + (wid << 10);   // wave-uniform dest
      GLOAD16(src, dst);
    }
  };
  auto LDA = [&](short8 (&af)[4][2], const u16* slot) {
    #pragma unroll
    for (int mi = 0; mi < 4; mi++)
      #pragma unroll
      for (int ks = 0; ks < 2; ks++)
        af[mi][ks] = ldsfrag(slot, wrow + mi * 16 + lr, ks, kg);
  };
  auto LDB = [&](short8 (&bf)[2][2], const u16* slot) {
    #pragma unroll
    for (int ni = 0; ni < 2; ni++)
      #pragma unroll
      for (int ks = 0; ks < 2; ks++)
        bf[ni][ks] = ldsfrag(slot, wcol + ni * 16 + lr, ks, kg);
  };
  auto MM = [&](f32x4 (&a)[4][2], short8 (&af)[4][2], short8 (&bf)[2][2]) {
    __builtin_amdgcn_s_setprio(1);
    #pragma unroll
    for (int ks = 0; ks < 2; ks++)
      #pragma unroll
      for (int mi = 0; mi < 4; mi++)
        #pragma unroll
        for (int ni = 0; ni < 2; ni++)
          a[mi][ni] = __builtin_amdgcn_mfma_f32_16x16x32_bf16(af[mi][ks], bf[ni][ks], a[mi][ni], 0, 0, 0);
    __builtin_amdgcn_s_setprio(0);
  };

  // prologue: stage T0 fully + T1 halves 0 (A,B); counted wait; barrier
  STAGE(Ap, 0, 0, Asl[0]); STAGE(Bp, 0, 0, Bsl[0]);
  STAGE(Ap, 0, 1, Asl[1]); STAGE(Bp, 0, 1, Bsl[1]);
  STAGE(Ap, 1, 0, Asl[2]); STAGE(Bp, 1, 0, Bsl[2]);
  asm volatile("s_waitcnt vmcnt(4)" ::: "memory");
  __builtin_amdgcn_s_barrier();

  short8 af[4][2], bf[2][2];
  int NI = NT >> 1;
  for (int I = 0; I < NI; I++) {
    int Tc = I * 2;
    int t1 = Tc + 1;
    int t2 = Tc + 2 < NT ? Tc + 2 : NT - 1;   // tail: clamp -> benign identical rewrite
    int t3 = Tc + 3 < NT ? Tc + 3 : NT - 1;
    u16* A2s0 = Asl[((t2 & 1) << 1) | 0]; u16* B2s0 = Bsl[((t2 & 1) << 1) | 0];
    u16* A2s1 = Asl[((t2 & 1) << 1) | 1]; u16* B2s1 = Bsl[((t2 & 1) << 1) | 1];
    u16* A3s0 = Asl[((t3 & 1) << 1) | 0]; u16* B3s0 = Bsl[((t3 & 1) << 1) | 0];
    // ph1: quad(0,0) of Tc
    LDA(af, Asl[0]); LDB(bf, Bsl[0]);
    STAGE(Ap, t1, 1, Asl[3]);
    __builtin_amdgcn_s_barrier();
    MM(acc[0][0], af, bf);
    __builtin_amdgcn_s_barrier();
    // ph2: quad(0,1)
    LDB(bf, Bsl[1]);
    STAGE(Bp, t1, 1, Bsl[3]);
    __builtin_amdgcn_s_barrier();
    MM(acc[0][1], af, bf);
    __builtin_amdgcn_s_barrier();
    // ph3: quad(1,0)
    LDA(af, Asl[1]); LDB(bf, Bsl[0]);
    STAGE(Ap, t2, 0, A2s0);
    __builtin_amdgcn_s_barrier();
    MM(acc[1][0], af, bf);
    __builtin_amdgcn_s_barrier();
    // ph4: quad(1,1)  [counted vmcnt -> T(c+1) fully landed]
    LDB(bf, Bsl[1]);
    STAGE(Bp, t2, 0, B2s0);
    asm volatile("s_waitcnt vmcnt(4)" ::: "memory");
    __builtin_amdgcn_s_barrier();
    MM(acc[1][1], af, bf);
    __builtin_amdgcn_s_barrier();
    // ph5: quad(0,0) of Tc+1
    LDA(af, Asl[2]); LDB(bf, Bsl[2]);
    STAGE(Ap, t2, 1, A2s1);
    __builtin_amdgcn_s_barrier();
    MM(acc[0][0], af, bf);
    __builtin_amdgcn_s_barrier();
    // ph6: quad(0,1)
    LDB(bf, Bsl[3]);
    STAGE(Bp, t2, 1, B2s1);
    __builtin_amdgcn_s_barrier();
    MM(acc[0][1], af, bf);
    __builtin_amdgcn_s_barrier();
    // ph7: quad(1,0)
    LDA(af, Asl[3]); LDB(bf, Bsl[2]);
    STAGE(Ap, t3, 0, A3s0);
    __builtin_amdgcn_s_barrier();
    MM(acc[1][0], af, bf);
    __builtin_amdgcn_s_barrier();
    // ph8: quad(1,1)  [counted vmcnt -> T(c+2) fully landed]
    LDB(bf, Bsl[3]);
    STAGE(Bp, t3, 0, B3s0);
    asm volatile("s_waitcnt vmcnt(4)" ::: "memory");
    __builtin_amdgcn_s_barrier();
    MM(acc[1][1], af, bf);
    __builtin_amdgcn_s_barrier();
  }
  // epilogue
  #pragma unroll
  for (int qm = 0; qm < 2; qm++)
    #pragma unroll
    for (int qn = 0; qn < 2; qn++)
      #pragma unroll
      for (int mi = 0; mi < 4; mi++)
        #pragma unroll
        for (int ni = 0; ni < 2; ni++) {
          int col = n0 + qn * 128 + wcol + ni * 16 + lr;
          int rbase = m0 + qm * 128 + wrow + mi * 16 + kg * 4;
          #pragma unroll
          for (int rr = 0; rr < 4; rr++) {
            int row = rbase + rr;
            float v = acc[qm][qn][mi][ni][rr];
            if (bq) v += row < 4096 ? bq[row] : (row < 5120 ? bk[row - 4096] : bv[row - 5120]);
            if (Cf) Cf[(size_t)row * N + col] = v;
            else    Cb[(size_t)row * N + col] = f2bf(v);
          }
        }
}

// ---------------- RoPE + transpose: in (nH*D, S) bf16 -> out (nH, S, D) bf16 ----------------
__global__ __launch_bounds__(256) void rope_transpose_kernel(const u16* __restrict__ in,
                                                             u16* __restrict__ out,
                                                             const float* __restrict__ cp,
                                                             const float* __restrict__ sp,
                                                             float oscale) {
  __shared__ u16 t[128][33];
  int h = blockIdx.x;
  int s0 = blockIdx.y * 32;
  int tid = threadIdx.x;
  #pragma unroll
  for (int i = 0; i < 16; i++) {
    int idx = tid + i * 256;
    int row = idx >> 5, sc = idx & 31;
    t[row][sc] = in[(size_t)(h * 128 + row) * S_ + s0 + sc];
  }
  __syncthreads();
  int d = tid & 127, sh = tid >> 7;
  int dl = d & 63;
  bool hi = d >= 64;
  #pragma unroll
  for (int j = 0; j < 16; j++) {
    int sl = sh * 16 + j;
    int s = s0 + sl;
    float x = bf2f(t[d][sl]);
    float p = bf2f(t[d ^ 64][sl]);
    float c  = cp[(size_t)s * D_ + dl];
    float sn = sp[(size_t)s * D_ + dl];
    float o = hi ? fmaf(p, sn, x * c) : fmaf(-p, sn, x * c);
    out[((size_t)h * S_ + s) * D_ + d] = f2bf(o * oscale);
  }
}

// ---------------- flash attention v2 (causal GQA, swapped-QK, staged KV) ----------------
__global__ __launch_bounds__(256) void attn_v2(const u16* __restrict__ Q, const u16* __restrict__ K,
                                               const u16* __restrict__ V, u16* __restrict__ Ot) {
  __shared__ alignas(16) u16 Ks[2][64 * 128];
  __shared__ alignas(16) u16 Vs[2][128 * 64];
  __shared__ alignas(16) u16 Pl[4][2][16 * 64];
  int h = blockIdx.x;
  int qtile = (int)(gridDim.y - 1) - (int)blockIdx.y;   // heavy first
  int kv = h >> 2;
  int tid = threadIdx.x, wid = tid >> 6, lane = tid & 63;
  int lr = lane & 15, kg = lane >> 4;
  int q0w = qtile * 128 + wid * 32;
  const u16* Qb = Q + ((size_t)h * S_ + q0w) * D_;
  const u16* Kb = K + (size_t)kv * S_ * D_;
  const u16* Vb = V + (size_t)kv * D_ * S_;
  int sw = (lr & 7) << 3;

  short8 qf[2][4];
  #pragma unroll
  for (int m = 0; m < 2; m++)
    #pragma unroll
    for (int kk = 0; kk < 4; kk++)
      qf[m][kk] = *(const short8a*)(Qb + (size_t)(m * 16 + lr) * D_ + kk * 32 + kg * 8);

  f32x4 acc[2][8] = {};
  float mreg[2] = {-1e30f, -1e30f};
  float lsum[2] = {0.f, 0.f};

  int krow[4], kcb[4], vrow[4], vcb[4];
  #pragma unroll
  for (int j = 0; j < 4; j++) {
    int c = wid * 4 + j;
    int o = c * 1024 + lane * 16;
    krow[j] = o >> 8;
    kcb[j] = (o & 255) ^ ((krow[j] & 7) << 4);
    vrow[j] = o >> 7;
    vcb[j] = (o & 127) ^ ((vrow[j] & 7) << 4);
  }

  int nlt = 2 * qtile + 2;
  #pragma unroll
  for (int j = 0; j < 4; j++) {
    int c = wid * 4 + j;
    GLOAD16((const char*)Kb + ((size_t)krow[j] * D_) * 2 + kcb[j], (char*)Ks[0] + c * 1024);
    GLOAD16((const char*)Vb + ((size_t)vrow[j] * S_) * 2 + vcb[j], (char*)Vs[0] + c * 1024);
  }
  int cur = 0;
  for (int t = 0; t < nlt; t++) {
    __syncthreads();
    if (t + 1 < nlt) {
      int l1 = (t + 1) * 64;
      #pragma unroll
      for (int j = 0; j < 4; j++) {
        int c = wid * 4 + j;
        GLOAD16((const char*)Kb + ((size_t)(l1 + krow[j]) * D_) * 2 + kcb[j],
                (char*)Ks[cur ^ 1] + c * 1024);
        GLOAD16((const char*)Vb + ((size_t)vrow[j] * S_ + l1) * 2 + vcb[j],
                (char*)Vs[cur ^ 1] + c * 1024);
      }
    }
    int l0 = t * 64;
    bool act0 = l0 <= q0w + 15;
    bool act1 = l0 <= q0w + 31;
    if (act1) {
      const u16* Kc = Ks[cur];
      const u16* Vc = Vs[cur];
      f32x4 st[2][4] = {};
      #pragma unroll
      for (int ls = 0; ls < 4; ls++) {
        short8 kf[4];
        #pragma unroll
        for (int kk = 0; kk < 4; kk++)
          kf[kk] = *(const short8a*)&Kc[(ls * 16 + lr) * 128 + ((kk * 32 + kg * 8) ^ sw)];
        #pragma unroll
        for (int kk = 0; kk < 4; kk++) {
          st[0][ls] = __builtin_amdgcn_mfma_f32_16x16x32_bf16(kf[kk], qf[0][kk], st[0][ls], 0, 0, 0);
          st[1][ls] = __builtin_amdgcn_mfma_f32_16x16x32_bf16(kf[kk], qf[1][kk], st[1][ls], 0, 0, 0);
        }
      }
      #pragma unroll
      for (int m = 0; m < 2; m++) {
        bool act = m ? act1 : act0;
        if (!act) continue;
        int qrow = q0w + m * 16 + lr;
        if (l0 + 63 > q0w + m * 16) {
          #pragma unroll
          for (int ls = 0; ls < 4; ls++)
            #pragma unroll
            for (int rr = 0; rr < 4; rr++) {
              int l = l0 + ls * 16 + kg * 4 + rr;
              st[m][ls][rr] = (l <= qrow) ? st[m][ls][rr] : -1e30f;
            }
        }
        float rmax;
        {
          float a0 = fmaxf(fmaxf(st[m][0][0], st[m][0][1]), fmaxf(st[m][0][2], st[m][0][3]));
          float a1 = fmaxf(fmaxf(st[m][1][0], st[m][1][1]), fmaxf(st[m][1][2], st[m][1][3]));
          float a2 = fmaxf(fmaxf(st[m][2][0], st[m][2][1]), fmaxf(st[m][2][2], st[m][2][3]));
          float a3 = fmaxf(fmaxf(st[m][3][0], st[m][3][1]), fmaxf(st[m][3][2], st[m][3][3]));
          rmax = fmaxf(fmaxf(a0, a1), fmaxf(a2, a3));
        }
        rmax = fmaxf(rmax, __shfl_xor(rmax, 16, 64));
        rmax = fmaxf(rmax, __shfl_xor(rmax, 32, 64));
        if (__any(rmax > mreg[m] + 8.0f)) {
          float nm = fmaxf(mreg[m], rmax);
          float f = __builtin_amdgcn_exp2f(mreg[m] - nm);
          mreg[m] = nm;
          lsum[m] *= f;
          float fr0 = __shfl(f, kg * 4 + 0, 64);
          float fr1 = __shfl(f, kg * 4 + 1, 64);
          float fr2 = __shfl(f, kg * 4 + 2, 64);
          float fr3 = __shfl(f, kg * 4 + 3, 64);
          #pragma unroll
          for (int dc = 0; dc < 8; dc++) {
            acc[m][dc][0] *= fr0; acc[m][dc][1] *= fr1;
            acc[m][dc][2] *= fr2; acc[m][dc][3] *= fr3;
          }
        }
        float e[4][4];
        #pragma unroll
        for (int ls = 0; ls < 4; ls++)
          #pragma unroll
          for (int rr = 0; rr < 4; rr++)
            e[ls][rr] = __builtin_amdgcn_exp2f(st[m][ls][rr] - mreg[m]);
        float rs = 0.f;
        #pragma unroll
        for (int ls = 0; ls < 4; ls++)
          rs += (e[ls][0] + e[ls][1]) + (e[ls][2] + e[ls][3]);
        rs += __shfl_xor(rs, 16, 64);
        rs += __shfl_xor(rs, 32, 64);
        lsum[m] += rs;
        u16* Pw = &Pl[wid][m][0];
        #pragma unroll
        for (int ls = 0; ls < 4; ls++) {
          __hip_bfloat162 p01 = __float22bfloat162_rn(float2{e[ls][0], e[ls][1]});
          __hip_bfloat162 p23 = __float22bfloat162_rn(float2{e[ls][2], e[ls][3]});
          uint2 pk;
          pk.x = *(u32*)&p01;
          pk.y = *(u32*)&p23;
          *(uint2*)&Pw[lr * 64 + ((ls * 16 + kg * 4) ^ sw)] = pk;
        }
      }
      #pragma unroll
      for (int kk = 0; kk < 2; kk++) {
        short8 pf0 = {}, pf1;
        if (act0) pf0 = *(const short8a*)&Pl[wid][0][lr * 64 + ((kk * 32 + kg * 8) ^ sw)];
        pf1 = *(const short8a*)&Pl[wid][1][lr * 64 + ((kk * 32 + kg * 8) ^ sw)];
        #pragma unroll
        for (int dc = 0; dc < 8; dc++) {
          short8 vf = *(const short8a*)&Vc[(dc * 16 + lr) * 64 + ((kk * 32 + kg * 8) ^ sw)];
          if (act0) acc[0][dc] = __builtin_amdgcn_mfma_f32_16x16x32_bf16(pf0, vf, acc[0][dc], 0, 0, 0);
          acc[1][dc] = __builtin_amdgcn_mfma_f32_16x16x32_bf16(pf1, vf, acc[1][dc], 0, 0, 0);
        }
      }
    }
    cur ^= 1;
  }
  #pragma unroll
  for (int m = 0; m < 2; m++) {
    float inv0 = 1.0f / __shfl(lsum[m], kg * 4 + 0, 64);
    float inv1 = 1.0f / __shfl(lsum[m], kg * 4 + 1, 64);
    float inv2 = 1.0f / __shfl(lsum[m], kg * 4 + 2, 64);
    float inv3 = 1.0f / __shfl(lsum[m], kg * 4 + 3, 64);
    #pragma unroll
    for (int dc = 0; dc < 8; dc++) {
      int col = h * D_ + dc * 16 + lr;
      int qg = q0w + m * 16 + kg * 4;
      Ot[(size_t)(qg + 0) * HID_ + col] = f2bf(acc[m][dc][0] * inv0);
      Ot[(size_t)(qg + 1) * HID_ + col] = f2bf(acc[m][dc][1] * inv1);
      Ot[(size_t)(qg + 2) * HID_ + col] = f2bf(acc[m][dc][2] * inv2);
      Ot[(size_t)(qg + 3) * HID_ + col] = f2bf(acc[m][dc][3] * inv3);
    }
  }
}

// ---------------- workspace layout (bytes) ----------------
static constexpr size_t OFF_WQKV = 0;           // 50331648 (6144x4096 bf16); reused post-QKV-gemm:
                                                //   QATT @0 (16.8MB), KATT @16777216 (4.2MB), OT @20971520 (16.8MB)
static constexpr size_t OFF_WO   = 50331648;    // 33554432 (4096x4096 bf16)
static constexpr size_t OFF_XT   = 83886080;    // 16777216 (2048x4096 bf16)
static constexpr size_t OFF_QKVC = 100663296;   // 25165824 (6144x2048 bf16) -> total 125829120

// log2(e)/sqrt(128): folds softmax scale + base-2 exp into Q
#define QSCALE 0.1275176329533421f

extern "C" void kernel_launch(void* const* d_in, const int* in_sizes, int n_in,
                              void* d_out, int out_size, void* d_ws, size_t ws_size,
                              hipStream_t stream) {
  const float* x    = (const float*)d_in[0];
  const float* wq   = (const float*)d_in[1];
  const float* bq   = (const float*)d_in[2];
  const float* wk   = (const float*)d_in[3];
  const float* bk   = (const float*)d_in[4];
  const float* wv   = (const float*)d_in[5];
  const float* bv   = (const float*)d_in[6];
  const float* wo   = (const float*)d_in[7];
  const float* cosP = (const float*)d_in[8];
  const float* sinP = (const float*)d_in[9];
  char* ws = (char*)d_ws;
  u16* WQKV = (u16*)(ws + OFF_WQKV);
  u16* WO   = (u16*)(ws + OFF_WO);
  u16* XT   = (u16*)(ws + OFF_XT);
  u16* QKVC = (u16*)(ws + OFF_QKVC);
  u16* QT   = QKVC;                         // rows 0..4095
  u16* KT   = QKVC + (size_t)4096 * S_;     // rows 4096..5119
  u16* VB   = QKVC + (size_t)5120 * S_;     // rows 5120..6143
  u16* QATT = (u16*)(ws + 0);               // WQKV dead after QKV gemm
  u16* KATT = (u16*)(ws + 16777216);
  u16* OT   = (u16*)(ws + 20971520);
  float* y = (float*)d_out;

  // 1) fused weight casts (wq,wk,wv stacked into WQKV; wo into WO)
  cast4_kernel<<<2048, 256, 0, stream>>>(
      wq, wk, wv, wo,
      WQKV, WQKV + (size_t)4096 * HID_, WQKV + (size_t)5120 * HID_, WO,
      (HID_ * HID_) / 4, (KV_ * D_ * HID_) / 4, (KV_ * D_ * HID_) / 4, (HID_ * HID_) / 4);
  // 2) X^T
  transpose_cast_kernel<<<dim3(S_ / 32, HID_ / 32), 256, 0, stream>>>(x, XT);
  // 3) fused QKV projection (M=6144), bias fused, bf16 out
  gemm256<<<dim3(S_ / 256, 6144 / 256), 512, 0, stream>>>(WQKV, XT, bq, bk, bv,
                                                          QKVC, nullptr, 6144, S_, HID_);
  // 4) RoPE + transpose (Q pre-scaled by log2e/sqrt(D))
  rope_transpose_kernel<<<dim3(H_, S_ / 32), 256, 0, stream>>>(QT, QATT, cosP, sinP, QSCALE);
  rope_transpose_kernel<<<dim3(KV_, S_ / 32), 256, 0, stream>>>(KT, KATT, cosP, sinP, 1.0f);
  // 5) causal GQA flash attention -> O^T (S, H*D)
  attn_v2<<<dim3(H_, S_ / 128), 256, 0, stream>>>(QATT, KATT, VB, OT);
  // 6) output projection -> fp32 d_out
  gemm256<<<dim3(S_ / 256, HID_ / 256), 512, 0, stream>>>(WO, OT, nullptr, nullptr, nullptr,
                                                          nullptr, y, HID_, S_, HID_);
}